// Round 10
// baseline (725.377 us; speedup 1.0000x reference)
//
#include <hip/hip_runtime.h>
#include <hip/hip_bf16.h>

typedef unsigned int uint;
typedef unsigned short ushort;
typedef short bf16x8 __attribute__((ext_vector_type(8)));
typedef float f32x4 __attribute__((ext_vector_type(4)));
typedef uint u32x4 __attribute__((ext_vector_type(4)));

#define NE 800000
#define NN 100000
#define TE 64
#define ASTR 168   // ushort row stride of input planes (336 B, 21x16B)
#define HSTR 136   // ushort row stride of hidden planes (272 B, 17x16B)
#define SA 164     // f32 row stride (gather-fallback kernel)
#define SH 132

// packed-weight offsets (ushort elems) in d_ws. Layout per layer (np in {0,1}):
// idx = base + (((np*KC + kc)*2 + plane)*NI + i)*512 + lane*8 + j
// value = W[k = kc*32 + (lane>>4)*8 + j][n = np*NI*16 + i*16 + (lane&15)]
// sizes: L0 (NI=4,KC=5)=40960, L1 (4,4)=32768, L2 (NI=2,KC=4)=16384
#define F0_OFF 0
#define F1_OFF 40960
#define F2_OFF 73728
#define T0_OFF 90112
#define T1_OFF 131072
#define T2_OFF 163840
#define WPK_TOTAL 180224
#define WPK_BYTES (WPK_TOTAL * 2)

__device__ __forceinline__ float ftanh(float x) {
    float cx = __builtin_amdgcn_fmed3f(x, -15.f, 15.f);          // clamp, 1 op
    float e = __builtin_amdgcn_exp2f(cx * 2.885390081777927f);   // exp(2*cx)
    return __builtin_fmaf(-2.f, __builtin_amdgcn_rcpf(e + 1.f), 1.f);  // 1 - 2/(e+1)
}

__device__ __forceinline__ void bfsplit(float x, ushort& hi, ushort& lo) {
    uint xb = __builtin_bit_cast(uint, x);
    hi = (ushort)(xb >> 16);
    float hif = __builtin_bit_cast(float, xb & 0xFFFF0000u);
    float res = x - hif;
    lo = (ushort)(__builtin_bit_cast(uint, res) >> 16);
}

__device__ __forceinline__ void split8(const float* v, bf16x8& fh, bf16x8& fl) {
    u32x4 H, L;
#pragma unroll
    for (int i = 0; i < 4; ++i) {
        ushort h0, l0, h1, l1;
        bfsplit(v[2*i],   h0, l0);
        bfsplit(v[2*i+1], h1, l1);
        H[i] = (uint)h0 | ((uint)h1 << 16);
        L[i] = (uint)l0 | ((uint)l1 << 16);
    }
    fh = __builtin_bit_cast(bf16x8, H);
    fl = __builtin_bit_cast(bf16x8, L);
}

// ---- weight pack: np-major (np in {0,1}), NI col-frags per wave ----
__global__ __launch_bounds__(256) void pack_w(
    const float* __restrict__ fW0, const float* __restrict__ fW1, const float* __restrict__ fW2,
    const float* __restrict__ tW0, const float* __restrict__ tW1, const float* __restrict__ tW2,
    ushort* __restrict__ wpk)
{
    int idx = blockIdx.x * 256 + threadIdx.x;   // < WPK_TOTAL
    const float* src; int NI, KC, Kact, base;
    if      (idx < F1_OFF) { src = fW0; NI = 4; KC = 5; Kact = 153; base = F0_OFF; }
    else if (idx < F2_OFF) { src = fW1; NI = 4; KC = 4; Kact = 128; base = F1_OFF; }
    else if (idx < T0_OFF) { src = fW2; NI = 2; KC = 4; Kact = 128; base = F2_OFF; }
    else if (idx < T1_OFF) { src = tW0; NI = 4; KC = 5; Kact = 153; base = T0_OFF; }
    else if (idx < T2_OFF) { src = tW1; NI = 4; KC = 4; Kact = 128; base = T1_OFF; }
    else                   { src = tW2; NI = 2; KC = 4; Kact = 128; base = T2_OFF; }
    int rel   = idx - base;
    int j     = rel & 7;
    int lane  = (rel >> 3) & 63;
    int sub   = rel >> 9;
    int i, plane, s2;
    if (NI == 4) { i = sub & 3; plane = (sub >> 2) & 1; s2 = sub >> 3; }
    else         { i = sub & 1; plane = (sub >> 1) & 1; s2 = sub >> 2; }
    int kc = s2 % KC;
    int np = s2 / KC;
    int k = kc * 32 + ((lane >> 4) << 3) + j;
    int n = np * (NI * 16) + i * 16 + (lane & 15);
    int N = 2 * NI * 16;
    float w = (k < Kact) ? src[(size_t)k * N + n] : 0.f;
    ushort hi, lo; bfsplit(w, hi, lo);
    wpk[idx] = plane ? lo : hi;
}

// ================= packed-weight main kernel =================
// Geometry: 8 waves = 4 mt-tiles (16 edge rows) x 2 np-tiles (NI*16 cols).
// Per kc per wave: 2 LDS A-reads (halved vs R8), 2*NI W-loads (np-partner
// waves stream identical fragments -> L1 broadcast), 3*NI MFMAs.
// W pipeline: depth-1 alternating 2-buffer (wb[(kc+1)&1] != wb[kc&1]); A dbuf.
// Chains: accM = bias + Ah*Wh; accC = Al*Wh + Ah*Wl.
template<int KC, int NI, bool INPLACE, bool SCATTER>
__device__ __forceinline__ void layer_p(
    const ushort* __restrict__ sAh, const ushort* __restrict__ sAl, int astr,
    const ushort* __restrict__ gW, const float* __restrict__ bias,
    ushort* __restrict__ sOh, ushort* __restrict__ sOl, int ostr,
    float* __restrict__ out, const int* __restrict__ s_nodes, int tid)
{
    const int lane = tid & 63;
    const int wave = tid >> 6;
    const int mt   = wave >> 1;          // 0..3
    const int np   = wave & 1;           // 0..1
    const int nn   = lane & 15;
    const int kq   = (lane >> 4) & 3;
    const ushort* apH = sAh + (mt * 16 + nn) * astr + kq * 8;
    const ushort* apL = sAl + (mt * 16 + nn) * astr + kq * 8;

    const int npu = __builtin_amdgcn_readfirstlane(np);
    const ushort* gWl = gW + (size_t)npu * (KC * 2 * NI * 512) + lane * 8;

    f32x4 accM[NI], accC[NI];
#pragma unroll
    for (int i = 0; i < NI; ++i) {
        float bv = bias[np * (NI * 16) + i * 16 + nn];
#pragma unroll
        for (int r = 0; r < 4; ++r) { accM[i][r] = bv; accC[i][r] = 0.f; }
    }

    bf16x8 wb[2][2 * NI];   // [buf][plane*NI + i]
    bf16x8 ab[2][2];        // [buf][0]=ah, [1]=al
    // prologue: W chunk 0, A chunk 0
#pragma unroll
    for (int p = 0; p < 2; ++p)
#pragma unroll
        for (int i = 0; i < NI; ++i)
            wb[0][p * NI + i] = *(const bf16x8*)(gWl + ((0 * 2 + p) * NI + i) * 512);
    ab[0][0] = *(const bf16x8*)(apH);
    ab[0][1] = *(const bf16x8*)(apL);

#pragma unroll
    for (int kc = 0; kc < KC; ++kc) {
        const int cw = kc & 1;
        const int ca = kc & 1;
        if (kc + 1 < KC) {
#pragma unroll
            for (int p = 0; p < 2; ++p)
#pragma unroll
                for (int i = 0; i < NI; ++i)
                    wb[cw ^ 1][p * NI + i] =
                        *(const bf16x8*)(gWl + (((kc + 1) * 2 + p) * NI + i) * 512);
            ab[ca ^ 1][0] = *(const bf16x8*)(apH + (kc + 1) * 32);
            ab[ca ^ 1][1] = *(const bf16x8*)(apL + (kc + 1) * 32);
        }
#pragma unroll
        for (int i = 0; i < NI; ++i)
            accM[i] = __builtin_amdgcn_mfma_f32_16x16x32_bf16(ab[ca][0], wb[cw][i], accM[i], 0, 0, 0);
#pragma unroll
        for (int i = 0; i < NI; ++i) {
            accC[i] = __builtin_amdgcn_mfma_f32_16x16x32_bf16(ab[ca][1], wb[cw][i], accC[i], 0, 0, 0);
            accC[i] = __builtin_amdgcn_mfma_f32_16x16x32_bf16(ab[ca][0], wb[cw][NI + i], accC[i], 0, 0, 0);
        }
    }

    if (INPLACE) __syncthreads();   // all reads of sO done before overwrite

#pragma unroll
    for (int i = 0; i < NI; ++i) {
        int n = np * (NI * 16) + i * 16 + nn;
#pragma unroll
        for (int r = 0; r < 4; ++r) {
            int m = mt * 16 + kq * 4 + r;   // C/D row map
            float h = ftanh(accM[i][r] + accC[i][r]);
            if (SCATTER) {
                unsafeAtomicAdd(out + (size_t)s_nodes[m] * 64 + n, h);
            } else {
                ushort hi, lo; bfsplit(h, hi, lo);
                sOh[m * ostr + n] = hi;
                sOl[m * ostr + n] = lo;
            }
        }
    }
}

__global__ __launch_bounds__(512, 4) void edge_mlp_packed(
    const int* __restrict__ af_, const int* __restrict__ at_,
    const float* __restrict__ h_local, const float* __restrict__ h_global,
    const float* __restrict__ x_local, const float* __restrict__ x_global,
    const float* __restrict__ tsc,
    const float* __restrict__ fb0, const float* __restrict__ fb1, const float* __restrict__ fb2,
    const float* __restrict__ tb0, const float* __restrict__ tb1, const float* __restrict__ tb2,
    const ushort* __restrict__ wpk, float* __restrict__ out)
{
    __shared__ ushort sAh[TE * ASTR], sAl[TE * ASTR];   // 21504 B each
    __shared__ ushort sHh[TE * HSTR], sHl[TE * HSTR];   // 17408 B each
    __shared__ int s_af[TE], s_at[TE];                  // total 78336 B

    const int tid = threadIdx.x;
    const int e = tid >> 3, part = tid & 7;
    const int eg = blockIdx.x * TE + e;
    {
        int af = af_[eg], at = at_[eg];
        if (part == 0) { s_af[e] = af; s_at[e] = at; }
        int node = (part < 4) ? af : at;
        int k0 = ((part & 3) << 4) + ((part < 4) ? 0 : 64);
        const float4* hp = (const float4*)(h_local + (size_t)node * 64 + ((part & 3) << 4));
        float4 q0 = hp[0], q1 = hp[1], q2 = hp[2], q3 = hp[3];
        float v[16] = {q0.x,q0.y,q0.z,q0.w, q1.x,q1.y,q1.z,q1.w,
                       q2.x,q2.y,q2.z,q2.w, q3.x,q3.y,q3.z,q3.w};
        u32x4 H0, H1, L0, L1;
#pragma unroll
        for (int i = 0; i < 4; ++i) {
            ushort h0, l0, h1, l1;
            bfsplit(v[2*i], h0, l0); bfsplit(v[2*i+1], h1, l1);
            H0[i] = (uint)h0 | ((uint)h1 << 16);
            L0[i] = (uint)l0 | ((uint)l1 << 16);
        }
#pragma unroll
        for (int i = 0; i < 4; ++i) {
            ushort h0, l0, h1, l1;
            bfsplit(v[8+2*i], h0, l0); bfsplit(v[8+2*i+1], h1, l1);
            H1[i] = (uint)h0 | ((uint)h1 << 16);
            L1[i] = (uint)l0 | ((uint)l1 << 16);
        }
        *(u32x4*)(sAh + e * ASTR + k0)     = H0;
        *(u32x4*)(sAh + e * ASTR + k0 + 8) = H1;
        *(u32x4*)(sAl + e * ASTR + k0)     = L0;
        *(u32x4*)(sAl + e * ASTR + k0 + 8) = L1;
        if (part < 2) {
            int k0t = 128 + part * 16;
            float w[16];
#pragma unroll
            for (int i = 0; i < 16; ++i) {
                int k = k0t + i;
                float x;
                if      (k < 132)  x = x_local[(size_t)eg * 4 + (k - 128)];
                else if (k < 148)  x = h_global[k - 132];
                else if (k < 152)  x = x_global[k - 148];
                else if (k == 152) x = tsc[0];
                else               x = 0.f;
                w[i] = x;
            }
            u32x4 H2, H3, L2, L3;
#pragma unroll
            for (int i = 0; i < 4; ++i) {
                ushort h0, l0, h1, l1;
                bfsplit(w[2*i], h0, l0); bfsplit(w[2*i+1], h1, l1);
                H2[i] = (uint)h0 | ((uint)h1 << 16);
                L2[i] = (uint)l0 | ((uint)l1 << 16);
            }
#pragma unroll
            for (int i = 0; i < 4; ++i) {
                ushort h0, l0, h1, l1;
                bfsplit(w[8+2*i], h0, l0); bfsplit(w[8+2*i+1], h1, l1);
                H3[i] = (uint)h0 | ((uint)h1 << 16);
                L3[i] = (uint)l0 | ((uint)l1 << 16);
            }
            *(u32x4*)(sAh + e * ASTR + k0t)     = H2;
            *(u32x4*)(sAh + e * ASTR + k0t + 8) = H3;
            *(u32x4*)(sAl + e * ASTR + k0t)     = L2;
            *(u32x4*)(sAl + e * ASTR + k0t + 8) = L3;
        }
    }
    __syncthreads();
    // f MLP
    layer_p<5,4,false,false>(sAh, sAl, ASTR, wpk + F0_OFF, fb0, sHh, sHl, HSTR, nullptr, nullptr, tid);
    __syncthreads();
    layer_p<4,4,true ,false>(sHh, sHl, HSTR, wpk + F1_OFF, fb1, sHh, sHl, HSTR, nullptr, nullptr, tid);
    __syncthreads();
    layer_p<4,2,false,true >(sHh, sHl, HSTR, wpk + F2_OFF, fb2, nullptr, nullptr, 0, out, s_af, tid);
    __syncthreads();
    // t MLP (sA planes intact)
    layer_p<5,4,false,false>(sAh, sAl, ASTR, wpk + T0_OFF, tb0, sHh, sHl, HSTR, nullptr, nullptr, tid);
    __syncthreads();
    layer_p<4,4,true ,false>(sHh, sHl, HSTR, wpk + T1_OFF, tb1, sHh, sHl, HSTR, nullptr, nullptr, tid);
    __syncthreads();
    layer_p<4,2,false,true >(sHh, sHl, HSTR, wpk + T2_OFF, tb2, nullptr, nullptr, 0, out, s_at, tid);
}

// ================= gather fallback (R4, verified passing) =================
template<int KC, int NT, int KACT, bool SCATTER>
__device__ __forceinline__ void layer(
    const float* __restrict__ sA, int astr,
    const float* __restrict__ gW, const float* __restrict__ bias,
    float* __restrict__ sO,
    float* __restrict__ out, const int* __restrict__ s_nodes, int tid)
{
    constexpr int NTW = NT / 2;
    constexpr int N = NT * 16;
    const int lane = tid & 63;
    const int wave = tid >> 6;
    const int mt   = wave >> 1;
    const int ntb  = (wave & 1) * NTW;
    const int arow = mt * 16 + (lane & 15);
    const int kg   = (lane >> 4) * 8;
    const int nn   = lane & 15;

    f32x4 aHH[NTW], aLH[NTW], aHL[NTW];
#pragma unroll
    for (int i = 0; i < NTW; ++i)
#pragma unroll
        for (int r = 0; r < 4; ++r) { aHH[i][r] = 0.f; aLH[i][r] = 0.f; aHL[i][r] = 0.f; }

#pragma unroll
    for (int kc = 0; kc < KC; ++kc) {
        const float* ap = sA + arow * astr + kc * 32 + kg;
        float av[8];
        float4 a0 = *(const float4*)ap;
        float4 a1 = *(const float4*)(ap + 4);
        av[0]=a0.x; av[1]=a0.y; av[2]=a0.z; av[3]=a0.w;
        av[4]=a1.x; av[5]=a1.y; av[6]=a1.z; av[7]=a1.w;
        bf16x8 ah, al; split8(av, ah, al);
#pragma unroll
        for (int i = 0; i < NTW; ++i) {
            int n = (ntb + i) * 16 + nn;
            float wv[8];
#pragma unroll
            for (int j = 0; j < 8; ++j) {
                int k = kc * 32 + kg + j;
                float w = 0.f;
                if (KC * 32 <= KACT || k < KACT)
                    w = gW[(size_t)k * N + n];
                wv[j] = w;
            }
            bf16x8 bh, bl; split8(wv, bh, bl);
            aHH[i] = __builtin_amdgcn_mfma_f32_16x16x32_bf16(ah, bh, aHH[i], 0, 0, 0);
            aLH[i] = __builtin_amdgcn_mfma_f32_16x16x32_bf16(al, bh, aLH[i], 0, 0, 0);
            aHL[i] = __builtin_amdgcn_mfma_f32_16x16x32_bf16(ah, bl, aHL[i], 0, 0, 0);
        }
    }

    if (!SCATTER) __syncthreads();

#pragma unroll
    for (int i = 0; i < NTW; ++i) {
        int n = (ntb + i) * 16 + nn;
        float bv = bias[n];
#pragma unroll
        for (int r = 0; r < 4; ++r) {
            int m = mt * 16 + ((lane >> 4) << 2) + r;
            float h = ftanh(aHH[i][r] + aLH[i][r] + aHL[i][r] + bv);
            if (SCATTER) {
                unsafeAtomicAdd(out + (size_t)s_nodes[m] * 64 + n, h);
            } else {
                sO[m * SH + n] = h;
            }
        }
    }
}

__global__ __launch_bounds__(512) void edge_mlp_gather(
    const int* __restrict__ af_, const int* __restrict__ at_,
    const float* __restrict__ h_local, const float* __restrict__ h_global,
    const float* __restrict__ x_local, const float* __restrict__ x_global,
    const float* __restrict__ tsc,
    const float* __restrict__ fW0, const float* __restrict__ fb0,
    const float* __restrict__ fW1, const float* __restrict__ fb1,
    const float* __restrict__ fW2, const float* __restrict__ fb2,
    const float* __restrict__ tW0, const float* __restrict__ tb0,
    const float* __restrict__ tW1, const float* __restrict__ tb1,
    const float* __restrict__ tW2, const float* __restrict__ tb2,
    float* __restrict__ out)
{
    __shared__ float sA[TE * SA];
    __shared__ float sH[TE * SH];
    __shared__ int s_af[TE], s_at[TE];

    const int tid = threadIdx.x;
    const int e = tid >> 3, part = tid & 7;
    const int eg = blockIdx.x * TE + e;
    {
        int af = af_[eg], at = at_[eg];
        if (part == 0) { s_af[e] = af; s_at[e] = at; }
        int node = (part < 4) ? af : at;
        int k0 = ((part & 3) << 4) + ((part < 4) ? 0 : 64);
        const float4* hp = (const float4*)(h_local + (size_t)node * 64 + ((part & 3) << 4));
        float4* dst = (float4*)(sA + e * SA + k0);
        dst[0] = hp[0]; dst[1] = hp[1]; dst[2] = hp[2]; dst[3] = hp[3];
        if (part < 2) {
            int k0t = 128 + part * 16;
#pragma unroll
            for (int i = 0; i < 16; ++i) {
                int k = k0t + i;
                float x;
                if      (k < 132)  x = x_local[(size_t)eg * 4 + (k - 128)];
                else if (k < 148)  x = h_global[k - 132];
                else if (k < 152)  x = x_global[k - 148];
                else if (k == 152) x = tsc[0];
                else               x = 0.f;
                sA[e * SA + k] = x;
            }
        }
    }
    __syncthreads();
    layer<5,8,153,false>(sA, SA, fW0, fb0, sH, nullptr, nullptr, tid);
    __syncthreads();
    layer<4,8,128,false>(sH, SH, fW1, fb1, sH, nullptr, nullptr, tid);
    __syncthreads();
    layer<4,4,128,true >(sH, SH, fW2, fb2, nullptr, out, s_af, tid);
    __syncthreads();
    layer<5,8,153,false>(sA, SA, tW0, tb0, sH, nullptr, nullptr, tid);
    __syncthreads();
    layer<4,8,128,false>(sH, SH, tW1, tb1, sH, nullptr, nullptr, tid);
    __syncthreads();
    layer<4,4,128,true >(sH, SH, tW2, tb2, nullptr, out, s_at, tid);
}

__global__ __launch_bounds__(256) void tanh_kernel(float* __restrict__ out, int n4) {
    int i = blockIdx.x * blockDim.x + threadIdx.x;
    int stride = gridDim.x * blockDim.x;
    float4* p = (float4*)out;
    for (; i < n4; i += stride) {
        float4 v = p[i];
        v.x = ftanh(v.x); v.y = ftanh(v.y); v.z = ftanh(v.z); v.w = ftanh(v.w);
        p[i] = v;
    }
}

extern "C" void kernel_launch(void* const* d_in, const int* in_sizes, int n_in,
                              void* d_out, int out_size, void* d_ws, size_t ws_size,
                              hipStream_t stream) {
    const int*   addr_from = (const int*)d_in[0];
    const int*   addr_to   = (const int*)d_in[1];
    const float* h_local   = (const float*)d_in[2];
    const float* h_global  = (const float*)d_in[3];
    const float* x_local   = (const float*)d_in[4];
    const float* x_global  = (const float*)d_in[5];
    const float* tsc       = (const float*)d_in[6];
    const float* fW0 = (const float*)d_in[7];
    const float* fb0 = (const float*)d_in[8];
    const float* fW1 = (const float*)d_in[9];
    const float* fb1 = (const float*)d_in[10];
    const float* fW2 = (const float*)d_in[11];
    const float* fb2 = (const float*)d_in[12];
    const float* tW0 = (const float*)d_in[13];
    const float* tb0 = (const float*)d_in[14];
    const float* tW1 = (const float*)d_in[15];
    const float* tb1 = (const float*)d_in[16];
    const float* tW2 = (const float*)d_in[17];
    const float* tb2 = (const float*)d_in[18];
    float* out = (float*)d_out;

    hipMemsetAsync(d_out, 0, (size_t)NN * 64 * sizeof(float), stream);

    if (ws_size >= (size_t)WPK_BYTES) {
        ushort* wpk = (ushort*)d_ws;
        pack_w<<<WPK_TOTAL / 256, 256, 0, stream>>>(fW0, fW1, fW2, tW0, tW1, tW2, wpk);
        edge_mlp_packed<<<NE / TE, 512, 0, stream>>>(
            addr_from, addr_to, h_local, h_global, x_local, x_global, tsc,
            fb0, fb1, fb2, tb0, tb1, tb2, wpk, out);
    } else {
        edge_mlp_gather<<<NE / TE, 512, 0, stream>>>(
            addr_from, addr_to, h_local, h_global, x_local, x_global, tsc,
            fW0, fb0, fW1, fb1, fW2, fb2, tW0, tb0, tW1, tb1, tW2, tb2, out);
    }
    tanh_kernel<<<2048, 256, 0, stream>>>(out, NN * 64 / 4);
}

// Round 11
// 513.475 us; speedup vs baseline: 1.4127x; 1.4127x over previous
//
#include <hip/hip_runtime.h>
#include <hip/hip_bf16.h>

typedef unsigned int uint;
typedef unsigned short ushort;
typedef _Float16 f16x8 __attribute__((ext_vector_type(8)));
typedef short bf16x8 __attribute__((ext_vector_type(8)));
typedef float f32x4 __attribute__((ext_vector_type(4)));
typedef uint u32x4 __attribute__((ext_vector_type(4)));

#define NE 800000
#define NN 100000
#define TE 64
#define ASTR 168   // ushort row stride of input planes (336 B, 21x16B)
#define HSTR 136   // ushort row stride of hidden planes (272 B, 17x16B)
#define SA 164     // f32 row stride (gather-fallback kernel)
#define SH 132

// packed fp16 weight offsets (ushort elems) in d_ws. Layout per layer:
// idx = base + ((np*KC + kc)*2 + i)*512 + lane*8 + j     (single fp16 plane)
// value = fp16( W[k = kc*32 + (lane>>4)*8 + j][n = np*32 + i*16 + (lane&15)] )
// sizes: L0 (NP=4,KC=5)=20480, L1 (4,4)=16384, L2 (NP=2,KC=4)=8192
#define F0_OFF 0
#define F1_OFF 20480
#define F2_OFF 36864
#define T0_OFF 45056
#define T1_OFF 65536
#define T2_OFF 81920
#define WPK_TOTAL 90112
#define WPK_BYTES (WPK_TOTAL * 2)

__device__ __forceinline__ float ftanh(float x) {
    float cx = __builtin_amdgcn_fmed3f(x, -15.f, 15.f);
    float e = __builtin_amdgcn_exp2f(cx * 2.885390081777927f);   // exp(2*cx)
    return __builtin_fmaf(-2.f, __builtin_amdgcn_rcpf(e + 1.f), 1.f);
}

// fp32 -> fp16 hi (RTNE) + fp16 lo (residual). (Ah+Al) carries ~2^-22 precision.
__device__ __forceinline__ void hsplit(float x, ushort& hi, ushort& lo) {
    _Float16 h = (_Float16)x;
    float r = x - (float)h;
    _Float16 l = (_Float16)r;
    hi = __builtin_bit_cast(ushort, h);
    lo = __builtin_bit_cast(ushort, l);
}

// bf16 split (gather-fallback kernel only)
__device__ __forceinline__ void bfsplit(float x, ushort& hi, ushort& lo) {
    uint xb = __builtin_bit_cast(uint, x);
    hi = (ushort)(xb >> 16);
    float hif = __builtin_bit_cast(float, xb & 0xFFFF0000u);
    float res = x - hif;
    lo = (ushort)(__builtin_bit_cast(uint, res) >> 16);
}

__device__ __forceinline__ void split8(const float* v, bf16x8& fh, bf16x8& fl) {
    u32x4 H, L;
#pragma unroll
    for (int i = 0; i < 4; ++i) {
        ushort h0, l0, h1, l1;
        bfsplit(v[2*i],   h0, l0);
        bfsplit(v[2*i+1], h1, l1);
        H[i] = (uint)h0 | ((uint)h1 << 16);
        L[i] = (uint)l0 | ((uint)l1 << 16);
    }
    fh = __builtin_bit_cast(bf16x8, H);
    fl = __builtin_bit_cast(bf16x8, L);
}

// ---- weight pack: single fp16 plane, wave-contiguous (R6-style layout) ----
__global__ __launch_bounds__(256) void pack_w(
    const float* __restrict__ fW0, const float* __restrict__ fW1, const float* __restrict__ fW2,
    const float* __restrict__ tW0, const float* __restrict__ tW1, const float* __restrict__ tW2,
    ushort* __restrict__ wpk)
{
    int idx = blockIdx.x * 256 + threadIdx.x;   // < WPK_TOTAL
    const float* src; int NP, KC, Kact, base;
    if      (idx < F1_OFF) { src = fW0; NP = 4; KC = 5; Kact = 153; base = F0_OFF; }
    else if (idx < F2_OFF) { src = fW1; NP = 4; KC = 4; Kact = 128; base = F1_OFF; }
    else if (idx < T0_OFF) { src = fW2; NP = 2; KC = 4; Kact = 128; base = F2_OFF; }
    else if (idx < T1_OFF) { src = tW0; NP = 4; KC = 5; Kact = 153; base = T0_OFF; }
    else if (idx < T2_OFF) { src = tW1; NP = 4; KC = 4; Kact = 128; base = T1_OFF; }
    else                   { src = tW2; NP = 2; KC = 4; Kact = 128; base = T2_OFF; }
    int rel  = idx - base;
    int j    = rel & 7;
    int lane = (rel >> 3) & 63;
    int sub  = rel >> 9;
    int i    = sub & 1;
    int s2   = sub >> 1;
    int kc   = s2 % KC;
    int np   = s2 / KC;
    int k = kc * 32 + ((lane >> 4) << 3) + j;
    int n = np * 32 + i * 16 + (lane & 15);
    int N = NP * 32;
    float w = (k < Kact) ? src[(size_t)k * N + n] : 0.f;
    _Float16 h = (_Float16)w;   // RTNE
    wpk[idx] = __builtin_bit_cast(ushort, h);
}

// ================= packed-weight main kernel (R8 structure, fp16) =================
// 8 waves: mt = wave>>2 (32 edge rows), np = wave&3 (32-col pair), active if np<NP.
// Depth-2 W prefetch into 3 rotating buffers ((kc+2)%3 != kc%3), A double-buffer.
// Chains (fp16): accM = bias + Ah*W; accC = Al*W  (W single fp16 plane).
template<int KC, int NP, bool INPLACE, bool SCATTER>
__device__ __forceinline__ void layer_p(
    const ushort* __restrict__ sAh, const ushort* __restrict__ sAl, int astr,
    const ushort* __restrict__ gW, const float* __restrict__ bias,
    ushort* __restrict__ sOh, ushort* __restrict__ sOl,
    float* __restrict__ out, const int* __restrict__ s_nodes, int tid)
{
    const int lane = tid & 63;
    const int wave = tid >> 6;
    const int mt   = wave >> 2;          // 0..1
    const int np   = wave & 3;           // 0..3
    const bool active = (np < NP);
    const int nn   = lane & 15;
    const int kq   = (lane >> 4) & 3;
    const ushort* apH = sAh + (mt * 32 + nn) * astr + kq * 8;
    const ushort* apL = sAl + (mt * 32 + nn) * astr + kq * 8;

    f32x4 accM[2][2], accC[2][2];

    if (active) {
        const int npu = __builtin_amdgcn_readfirstlane(np);
        const ushort* gWl = gW + (size_t)npu * (KC * 1024) + lane * 8;

        // bias into main accumulator, corr chain zero
#pragma unroll
        for (int mi = 0; mi < 2; ++mi)
#pragma unroll
            for (int ni = 0; ni < 2; ++ni) {
                float bv = bias[np * 32 + ni * 16 + nn];
#pragma unroll
                for (int r = 0; r < 4; ++r) { accM[mi][ni][r] = bv; accC[mi][ni][r] = 0.f; }
            }

        f16x8 wb[3][2];
        f16x8 ab[2][4];   // [buf][0]=ah mi0, [1]=ah mi1, [2]=al mi0, [3]=al mi1
        // prologue: W chunks 0,1 (depth-2), A chunk 0
#pragma unroll
        for (int d = 0; d < 2; ++d) {
#pragma unroll
            for (int j = 0; j < 2; ++j)
                wb[d][j] = *(const f16x8*)(gWl + (d * 2 + j) * 512);
        }
        ab[0][0] = *(const f16x8*)(apH);
        ab[0][1] = *(const f16x8*)(apH + 16 * astr);
        ab[0][2] = *(const f16x8*)(apL);
        ab[0][3] = *(const f16x8*)(apL + 16 * astr);

#pragma unroll
        for (int kc = 0; kc < KC; ++kc) {
            const int cw = kc % 3;
            const int ca = kc & 1;
            if (kc + 2 < KC) {
#pragma unroll
                for (int j = 0; j < 2; ++j)
                    wb[(kc + 2) % 3][j] = *(const f16x8*)(gWl + ((kc + 2) * 2 + j) * 512);
            }
            if (kc + 1 < KC) {
                ab[ca ^ 1][0] = *(const f16x8*)(apH + (kc + 1) * 32);
                ab[ca ^ 1][1] = *(const f16x8*)(apH + 16 * astr + (kc + 1) * 32);
                ab[ca ^ 1][2] = *(const f16x8*)(apL + (kc + 1) * 32);
                ab[ca ^ 1][3] = *(const f16x8*)(apL + 16 * astr + (kc + 1) * 32);
            }
#pragma unroll
            for (int mi = 0; mi < 2; ++mi)
#pragma unroll
                for (int ni = 0; ni < 2; ++ni)
                    accM[mi][ni] = __builtin_amdgcn_mfma_f32_16x16x32_f16(ab[ca][mi], wb[cw][ni], accM[mi][ni], 0, 0, 0);
#pragma unroll
            for (int mi = 0; mi < 2; ++mi)
#pragma unroll
                for (int ni = 0; ni < 2; ++ni)
                    accC[mi][ni] = __builtin_amdgcn_mfma_f32_16x16x32_f16(ab[ca][2 + mi], wb[cw][ni], accC[mi][ni], 0, 0, 0);
        }
    }

    if (INPLACE) __syncthreads();   // all reads of sO done before overwrite

    if (active) {
#pragma unroll
        for (int mi = 0; mi < 2; ++mi)
#pragma unroll
            for (int ni = 0; ni < 2; ++ni) {
                int n = np * 32 + ni * 16 + nn;
#pragma unroll
                for (int r = 0; r < 4; ++r) {
                    int m = mt * 32 + mi * 16 + kq * 4 + r;  // C/D row map
                    float h = ftanh(accM[mi][ni][r] + accC[mi][ni][r]);
                    if (SCATTER) {
                        unsafeAtomicAdd(out + (size_t)s_nodes[m] * 64 + n, h);
                    } else {
                        ushort hi, lo; hsplit(h, hi, lo);
                        sOh[m * HSTR + n] = hi;
                        sOl[m * HSTR + n] = lo;
                    }
                }
            }
    }
}

__global__ __launch_bounds__(512, 4) void edge_mlp_packed(
    const int* __restrict__ af_, const int* __restrict__ at_,
    const float* __restrict__ h_local, const float* __restrict__ h_global,
    const float* __restrict__ x_local, const float* __restrict__ x_global,
    const float* __restrict__ tsc,
    const float* __restrict__ fb0, const float* __restrict__ fb1, const float* __restrict__ fb2,
    const float* __restrict__ tb0, const float* __restrict__ tb1, const float* __restrict__ tb2,
    const ushort* __restrict__ wpk, float* __restrict__ out)
{
    __shared__ ushort sAh[TE * ASTR], sAl[TE * ASTR];   // 21504 B each
    __shared__ ushort sHh[TE * HSTR], sHl[TE * HSTR];   // 17408 B each
    __shared__ int s_af[TE], s_at[TE];                  // total 78336 B

    const int tid = threadIdx.x;
    const int e = tid >> 3, part = tid & 7;
    const int eg = blockIdx.x * TE + e;
    {
        int af = af_[eg], at = at_[eg];
        if (part == 0) { s_af[e] = af; s_at[e] = at; }
        int node = (part < 4) ? af : at;
        int k0 = ((part & 3) << 4) + ((part < 4) ? 0 : 64);
        const float4* hp = (const float4*)(h_local + (size_t)node * 64 + ((part & 3) << 4));
        float4 q0 = hp[0], q1 = hp[1], q2 = hp[2], q3 = hp[3];
        float v[16] = {q0.x,q0.y,q0.z,q0.w, q1.x,q1.y,q1.z,q1.w,
                       q2.x,q2.y,q2.z,q2.w, q3.x,q3.y,q3.z,q3.w};
        u32x4 H0, H1, L0, L1;
#pragma unroll
        for (int i = 0; i < 4; ++i) {
            ushort h0, l0, h1, l1;
            hsplit(v[2*i], h0, l0); hsplit(v[2*i+1], h1, l1);
            H0[i] = (uint)h0 | ((uint)h1 << 16);
            L0[i] = (uint)l0 | ((uint)l1 << 16);
        }
#pragma unroll
        for (int i = 0; i < 4; ++i) {
            ushort h0, l0, h1, l1;
            hsplit(v[8+2*i], h0, l0); hsplit(v[8+2*i+1], h1, l1);
            H1[i] = (uint)h0 | ((uint)h1 << 16);
            L1[i] = (uint)l0 | ((uint)l1 << 16);
        }
        *(u32x4*)(sAh + e * ASTR + k0)     = H0;
        *(u32x4*)(sAh + e * ASTR + k0 + 8) = H1;
        *(u32x4*)(sAl + e * ASTR + k0)     = L0;
        *(u32x4*)(sAl + e * ASTR + k0 + 8) = L1;
        if (part < 2) {
            int k0t = 128 + part * 16;
            float w[16];
#pragma unroll
            for (int i = 0; i < 16; ++i) {
                int k = k0t + i;
                float x;
                if      (k < 132)  x = x_local[(size_t)eg * 4 + (k - 128)];
                else if (k < 148)  x = h_global[k - 132];
                else if (k < 152)  x = x_global[k - 148];
                else if (k == 152) x = tsc[0];
                else               x = 0.f;
                w[i] = x;
            }
            u32x4 H2, H3, L2, L3;
#pragma unroll
            for (int i = 0; i < 4; ++i) {
                ushort h0, l0, h1, l1;
                hsplit(w[2*i], h0, l0); hsplit(w[2*i+1], h1, l1);
                H2[i] = (uint)h0 | ((uint)h1 << 16);
                L2[i] = (uint)l0 | ((uint)l1 << 16);
            }
#pragma unroll
            for (int i = 0; i < 4; ++i) {
                ushort h0, l0, h1, l1;
                hsplit(w[8+2*i], h0, l0); hsplit(w[8+2*i+1], h1, l1);
                H3[i] = (uint)h0 | ((uint)h1 << 16);
                L3[i] = (uint)l0 | ((uint)l1 << 16);
            }
            *(u32x4*)(sAh + e * ASTR + k0t)     = H2;
            *(u32x4*)(sAh + e * ASTR + k0t + 8) = H3;
            *(u32x4*)(sAl + e * ASTR + k0t)     = L2;
            *(u32x4*)(sAl + e * ASTR + k0t + 8) = L3;
        }
    }
    __syncthreads();
    // f MLP
    layer_p<5,4,false,false>(sAh, sAl, ASTR, wpk + F0_OFF, fb0, sHh, sHl, nullptr, nullptr, tid);
    __syncthreads();
    layer_p<4,4,true ,false>(sHh, sHl, HSTR, wpk + F1_OFF, fb1, sHh, sHl, nullptr, nullptr, tid);
    __syncthreads();
    layer_p<4,2,false,true >(sHh, sHl, HSTR, wpk + F2_OFF, fb2, nullptr, nullptr, out, s_af, tid);
    __syncthreads();
    // t MLP (sA planes intact)
    layer_p<5,4,false,false>(sAh, sAl, ASTR, wpk + T0_OFF, tb0, sHh, sHl, nullptr, nullptr, tid);
    __syncthreads();
    layer_p<4,4,true ,false>(sHh, sHl, HSTR, wpk + T1_OFF, tb1, sHh, sHl, nullptr, nullptr, tid);
    __syncthreads();
    layer_p<4,2,false,true >(sHh, sHl, HSTR, wpk + T2_OFF, tb2, nullptr, nullptr, out, s_at, tid);
}

// ================= gather fallback (R4, verified passing; bf16 3-chain) =================
template<int KC, int NT, int KACT, bool SCATTER>
__device__ __forceinline__ void layer(
    const float* __restrict__ sA, int astr,
    const float* __restrict__ gW, const float* __restrict__ bias,
    float* __restrict__ sO,
    float* __restrict__ out, const int* __restrict__ s_nodes, int tid)
{
    constexpr int NTW = NT / 2;
    constexpr int N = NT * 16;
    const int lane = tid & 63;
    const int wave = tid >> 6;
    const int mt   = wave >> 1;
    const int ntb  = (wave & 1) * NTW;
    const int arow = mt * 16 + (lane & 15);
    const int kg   = (lane >> 4) * 8;
    const int nn   = lane & 15;

    f32x4 aHH[NTW], aLH[NTW], aHL[NTW];
#pragma unroll
    for (int i = 0; i < NTW; ++i)
#pragma unroll
        for (int r = 0; r < 4; ++r) { aHH[i][r] = 0.f; aLH[i][r] = 0.f; aHL[i][r] = 0.f; }

#pragma unroll
    for (int kc = 0; kc < KC; ++kc) {
        const float* ap = sA + arow * astr + kc * 32 + kg;
        float av[8];
        float4 a0 = *(const float4*)ap;
        float4 a1 = *(const float4*)(ap + 4);
        av[0]=a0.x; av[1]=a0.y; av[2]=a0.z; av[3]=a0.w;
        av[4]=a1.x; av[5]=a1.y; av[6]=a1.z; av[7]=a1.w;
        bf16x8 ah, al; split8(av, ah, al);
#pragma unroll
        for (int i = 0; i < NTW; ++i) {
            int n = (ntb + i) * 16 + nn;
            float wv[8];
#pragma unroll
            for (int j = 0; j < 8; ++j) {
                int k = kc * 32 + kg + j;
                float w = 0.f;
                if (KC * 32 <= KACT || k < KACT)
                    w = gW[(size_t)k * N + n];
                wv[j] = w;
            }
            bf16x8 bh, bl; split8(wv, bh, bl);
            aHH[i] = __builtin_amdgcn_mfma_f32_16x16x32_bf16(ah, bh, aHH[i], 0, 0, 0);
            aLH[i] = __builtin_amdgcn_mfma_f32_16x16x32_bf16(al, bh, aLH[i], 0, 0, 0);
            aHL[i] = __builtin_amdgcn_mfma_f32_16x16x32_bf16(ah, bl, aHL[i], 0, 0, 0);
        }
    }

    if (!SCATTER) __syncthreads();

#pragma unroll
    for (int i = 0; i < NTW; ++i) {
        int n = (ntb + i) * 16 + nn;
        float bv = bias[n];
#pragma unroll
        for (int r = 0; r < 4; ++r) {
            int m = mt * 16 + ((lane >> 4) << 2) + r;
            float h = ftanh(aHH[i][r] + aLH[i][r] + aHL[i][r] + bv);
            if (SCATTER) {
                unsafeAtomicAdd(out + (size_t)s_nodes[m] * 64 + n, h);
            } else {
                sO[m * SH + n] = h;
            }
        }
    }
}

__global__ __launch_bounds__(512) void edge_mlp_gather(
    const int* __restrict__ af_, const int* __restrict__ at_,
    const float* __restrict__ h_local, const float* __restrict__ h_global,
    const float* __restrict__ x_local, const float* __restrict__ x_global,
    const float* __restrict__ tsc,
    const float* __restrict__ fW0, const float* __restrict__ fb0,
    const float* __restrict__ fW1, const float* __restrict__ fb1,
    const float* __restrict__ fW2, const float* __restrict__ fb2,
    const float* __restrict__ tW0, const float* __restrict__ tb0,
    const float* __restrict__ tW1, const float* __restrict__ tb1,
    const float* __restrict__ tW2, const float* __restrict__ tb2,
    float* __restrict__ out)
{
    __shared__ float sA[TE * SA];
    __shared__ float sH[TE * SH];
    __shared__ int s_af[TE], s_at[TE];

    const int tid = threadIdx.x;
    const int e = tid >> 3, part = tid & 7;
    const int eg = blockIdx.x * TE + e;
    {
        int af = af_[eg], at = at_[eg];
        if (part == 0) { s_af[e] = af; s_at[e] = at; }
        int node = (part < 4) ? af : at;
        int k0 = ((part & 3) << 4) + ((part < 4) ? 0 : 64);
        const float4* hp = (const float4*)(h_local + (size_t)node * 64 + ((part & 3) << 4));
        float4* dst = (float4*)(sA + e * SA + k0);
        dst[0] = hp[0]; dst[1] = hp[1]; dst[2] = hp[2]; dst[3] = hp[3];
        if (part < 2) {
            int k0t = 128 + part * 16;
#pragma unroll
            for (int i = 0; i < 16; ++i) {
                int k = k0t + i;
                float x;
                if      (k < 132)  x = x_local[(size_t)eg * 4 + (k - 128)];
                else if (k < 148)  x = h_global[k - 132];
                else if (k < 152)  x = x_global[k - 148];
                else if (k == 152) x = tsc[0];
                else               x = 0.f;
                sA[e * SA + k] = x;
            }
        }
    }
    __syncthreads();
    layer<5,8,153,false>(sA, SA, fW0, fb0, sH, nullptr, nullptr, tid);
    __syncthreads();
    layer<4,8,128,false>(sH, SH, fW1, fb1, sH, nullptr, nullptr, tid);
    __syncthreads();
    layer<4,4,128,true >(sH, SH, fW2, fb2, nullptr, out, s_af, tid);
    __syncthreads();
    layer<5,8,153,false>(sA, SA, tW0, tb0, sH, nullptr, nullptr, tid);
    __syncthreads();
    layer<4,8,128,false>(sH, SH, tW1, tb1, sH, nullptr, nullptr, tid);
    __syncthreads();
    layer<4,4,128,true >(sH, SH, tW2, tb2, nullptr, out, s_at, tid);
}

__global__ __launch_bounds__(256) void tanh_kernel(float* __restrict__ out, int n4) {
    int i = blockIdx.x * blockDim.x + threadIdx.x;
    int stride = gridDim.x * blockDim.x;
    float4* p = (float4*)out;
    for (; i < n4; i += stride) {
        float4 v = p[i];
        v.x = ftanh(v.x); v.y = ftanh(v.y); v.z = ftanh(v.z); v.w = ftanh(v.w);
        p[i] = v;
    }
}

extern "C" void kernel_launch(void* const* d_in, const int* in_sizes, int n_in,
                              void* d_out, int out_size, void* d_ws, size_t ws_size,
                              hipStream_t stream) {
    const int*   addr_from = (const int*)d_in[0];
    const int*   addr_to   = (const int*)d_in[1];
    const float* h_local   = (const float*)d_in[2];
    const float* h_global  = (const float*)d_in[3];
    const float* x_local   = (const float*)d_in[4];
    const float* x_global  = (const float*)d_in[5];
    const float* tsc       = (const float*)d_in[6];
    const float* fW0 = (const float*)d_in[7];
    const float* fb0 = (const float*)d_in[8];
    const float* fW1 = (const float*)d_in[9];
    const float* fb1 = (const float*)d_in[10];
    const float* fW2 = (const float*)d_in[11];
    const float* fb2 = (const float*)d_in[12];
    const float* tW0 = (const float*)d_in[13];
    const float* tb0 = (const float*)d_in[14];
    const float* tW1 = (const float*)d_in[15];
    const float* tb1 = (const float*)d_in[16];
    const float* tW2 = (const float*)d_in[17];
    const float* tb2 = (const float*)d_in[18];
    float* out = (float*)d_out;

    hipMemsetAsync(d_out, 0, (size_t)NN * 64 * sizeof(float), stream);

    if (ws_size >= (size_t)WPK_BYTES) {
        ushort* wpk = (ushort*)d_ws;
        pack_w<<<WPK_TOTAL / 256, 256, 0, stream>>>(fW0, fW1, fW2, tW0, tW1, tW2, wpk);
        edge_mlp_packed<<<NE / TE, 512, 0, stream>>>(
            addr_from, addr_to, h_local, h_global, x_local, x_global, tsc,
            fb0, fb1, fb2, tb0, tb1, tb2, wpk, out);
    } else {
        edge_mlp_gather<<<NE / TE, 512, 0, stream>>>(
            addr_from, addr_to, h_local, h_global, x_local, x_global, tsc,
            fW0, fb0, fW1, fb1, fW2, fb2, tW0, tb0, tW1, tb1, tW2, tb2, out);
    }
    tanh_kernel<<<2048, 256, 0, stream>>>(out, NN * 64 / 4);
}

// Round 12
// 432.063 us; speedup vs baseline: 1.6789x; 1.1884x over previous
//
#include <hip/hip_runtime.h>
#include <hip/hip_bf16.h>

typedef unsigned int uint;
typedef unsigned short ushort;
typedef _Float16 f16x8 __attribute__((ext_vector_type(8)));
typedef short bf16x8 __attribute__((ext_vector_type(8)));
typedef float f32x4 __attribute__((ext_vector_type(4)));
typedef uint u32x4 __attribute__((ext_vector_type(4)));

#define NE 800000
#define NN 100000
#define TE 64
#define ASTR 168   // ushort row stride of input planes (336 B, 21x16B)
#define HSTR 136   // ushort row stride of hidden plane (272 B, 17x16B)
#define SA 164     // f32 row stride (gather-fallback kernel)
#define SH 132

// packed fp16 weight offsets (ushort elems) in d_ws — R11 layout (verified):
// idx = base + ((np*KC + kc)*2 + i)*512 + lane*8 + j     (single fp16 plane)
// value = fp16( W[k = kc*32 + (lane>>4)*8 + j][n = np*32 + i*16 + (lane&15)] )
#define F0_OFF 0
#define F1_OFF 20480
#define F2_OFF 36864
#define T0_OFF 45056
#define T1_OFF 65536
#define T2_OFF 81920
#define WPK_TOTAL 90112
#define WPK_BYTES (WPK_TOTAL * 2)

__device__ __forceinline__ float ftanh(float x) {
    float cx = __builtin_amdgcn_fmed3f(x, -15.f, 15.f);
    float e = __builtin_amdgcn_exp2f(cx * 2.885390081777927f);   // exp(2*cx)
    return __builtin_fmaf(-2.f, __builtin_amdgcn_rcpf(e + 1.f), 1.f);
}

// fp32 -> fp16 hi (RTNE) + fp16 lo (residual)
__device__ __forceinline__ void hsplit(float x, ushort& hi, ushort& lo) {
    _Float16 h = (_Float16)x;
    float r = x - (float)h;
    _Float16 l = (_Float16)r;
    hi = __builtin_bit_cast(ushort, h);
    lo = __builtin_bit_cast(ushort, l);
}

// bf16 split (gather-fallback kernel only)
__device__ __forceinline__ void bfsplit(float x, ushort& hi, ushort& lo) {
    uint xb = __builtin_bit_cast(uint, x);
    hi = (ushort)(xb >> 16);
    float hif = __builtin_bit_cast(float, xb & 0xFFFF0000u);
    float res = x - hif;
    lo = (ushort)(__builtin_bit_cast(uint, res) >> 16);
}

__device__ __forceinline__ void split8(const float* v, bf16x8& fh, bf16x8& fl) {
    u32x4 H, L;
#pragma unroll
    for (int i = 0; i < 4; ++i) {
        ushort h0, l0, h1, l1;
        bfsplit(v[2*i],   h0, l0);
        bfsplit(v[2*i+1], h1, l1);
        H[i] = (uint)h0 | ((uint)h1 << 16);
        L[i] = (uint)l0 | ((uint)l1 << 16);
    }
    fh = __builtin_bit_cast(bf16x8, H);
    fl = __builtin_bit_cast(bf16x8, L);
}

// ---- weight pack: single fp16 plane, wave-contiguous — unchanged from R11 ----
__global__ __launch_bounds__(256) void pack_w(
    const float* __restrict__ fW0, const float* __restrict__ fW1, const float* __restrict__ fW2,
    const float* __restrict__ tW0, const float* __restrict__ tW1, const float* __restrict__ tW2,
    ushort* __restrict__ wpk)
{
    int idx = blockIdx.x * 256 + threadIdx.x;   // < WPK_TOTAL
    const float* src; int NP, KC, Kact, base;
    if      (idx < F1_OFF) { src = fW0; NP = 4; KC = 5; Kact = 153; base = F0_OFF; }
    else if (idx < F2_OFF) { src = fW1; NP = 4; KC = 4; Kact = 128; base = F1_OFF; }
    else if (idx < T0_OFF) { src = fW2; NP = 2; KC = 4; Kact = 128; base = F2_OFF; }
    else if (idx < T1_OFF) { src = tW0; NP = 4; KC = 5; Kact = 153; base = T0_OFF; }
    else if (idx < T2_OFF) { src = tW1; NP = 4; KC = 4; Kact = 128; base = T1_OFF; }
    else                   { src = tW2; NP = 2; KC = 4; Kact = 128; base = T2_OFF; }
    int rel  = idx - base;
    int j    = rel & 7;
    int lane = (rel >> 3) & 63;
    int sub  = rel >> 9;
    int i    = sub & 1;
    int s2   = sub >> 1;
    int kc   = s2 % KC;
    int np   = s2 / KC;
    int k = kc * 32 + ((lane >> 4) << 3) + j;
    int n = np * 32 + i * 16 + (lane & 15);
    int N = NP * 32;
    float w = (k < Kact) ? src[(size_t)k * N + n] : 0.f;
    _Float16 h = (_Float16)w;   // RTNE
    wpk[idx] = __builtin_bit_cast(ushort, h);
}

// ================= packed-weight main kernel =================
// R8/R11 geometry: 8 waves, mt = wave>>2 (32 edge rows), np = wave&3 (32 cols),
// active if np<NP. Depth-2 W prefetch, 3 rotating buffers; A double-buffer.
// ALO (input layer): A = fp16 hi+lo planes, 2 chains (accM=bias+Ah*W, accC=Al*W).
// !ALO (hidden layers, tanh-bounded): A = single fp16 plane, 1 chain.
template<int KC, int NP, bool ALO, bool INPLACE, bool SCATTER>
__device__ __forceinline__ void layer_p(
    const ushort* __restrict__ sAh, const ushort* __restrict__ sAl, int astr,
    const ushort* __restrict__ gW, const float* __restrict__ bias,
    ushort* __restrict__ sOh,
    float* __restrict__ out, const int* __restrict__ s_nodes, int tid)
{
    constexpr int AB = ALO ? 4 : 2;
    const int lane = tid & 63;
    const int wave = tid >> 6;
    const int mt   = wave >> 2;          // 0..1
    const int np   = wave & 3;           // 0..3
    const bool active = (np < NP);
    const int nn   = lane & 15;
    const int kq   = (lane >> 4) & 3;
    const ushort* apH = sAh + (mt * 32 + nn) * astr + kq * 8;
    const ushort* apL = ALO ? (sAl + (mt * 32 + nn) * astr + kq * 8) : nullptr;

    f32x4 accM[2][2], accC[2][2];

    if (active) {
        const int npu = __builtin_amdgcn_readfirstlane(np);
        const ushort* gWl = gW + (size_t)npu * (KC * 1024) + lane * 8;

#pragma unroll
        for (int mi = 0; mi < 2; ++mi)
#pragma unroll
            for (int ni = 0; ni < 2; ++ni) {
                float bv = bias[np * 32 + ni * 16 + nn];
#pragma unroll
                for (int r = 0; r < 4; ++r) { accM[mi][ni][r] = bv; accC[mi][ni][r] = 0.f; }
            }

        f16x8 wb[3][2];
        f16x8 ab[2][AB];   // [buf][0]=ah mi0, [1]=ah mi1, (+ [2],[3]=al if ALO)
        // prologue: W chunks 0,1 (depth-2), A chunk 0
#pragma unroll
        for (int d = 0; d < 2; ++d) {
#pragma unroll
            for (int j = 0; j < 2; ++j)
                wb[d][j] = *(const f16x8*)(gWl + (d * 2 + j) * 512);
        }
        ab[0][0] = *(const f16x8*)(apH);
        ab[0][1] = *(const f16x8*)(apH + 16 * astr);
        if (ALO) {
            ab[0][2] = *(const f16x8*)(apL);
            ab[0][3] = *(const f16x8*)(apL + 16 * astr);
        }

#pragma unroll
        for (int kc = 0; kc < KC; ++kc) {
            const int cw = kc % 3;
            const int ca = kc & 1;
            if (kc + 2 < KC) {
#pragma unroll
                for (int j = 0; j < 2; ++j)
                    wb[(kc + 2) % 3][j] = *(const f16x8*)(gWl + ((kc + 2) * 2 + j) * 512);
            }
            if (kc + 1 < KC) {
                ab[ca ^ 1][0] = *(const f16x8*)(apH + (kc + 1) * 32);
                ab[ca ^ 1][1] = *(const f16x8*)(apH + 16 * astr + (kc + 1) * 32);
                if (ALO) {
                    ab[ca ^ 1][2] = *(const f16x8*)(apL + (kc + 1) * 32);
                    ab[ca ^ 1][3] = *(const f16x8*)(apL + 16 * astr + (kc + 1) * 32);
                }
            }
#pragma unroll
            for (int mi = 0; mi < 2; ++mi)
#pragma unroll
                for (int ni = 0; ni < 2; ++ni)
                    accM[mi][ni] = __builtin_amdgcn_mfma_f32_16x16x32_f16(ab[ca][mi], wb[cw][ni], accM[mi][ni], 0, 0, 0);
            if (ALO) {
#pragma unroll
                for (int mi = 0; mi < 2; ++mi)
#pragma unroll
                    for (int ni = 0; ni < 2; ++ni)
                        accC[mi][ni] = __builtin_amdgcn_mfma_f32_16x16x32_f16(ab[ca][2 + mi], wb[cw][ni], accC[mi][ni], 0, 0, 0);
            }
        }
    }

    if (INPLACE) __syncthreads();   // all reads of sO done before overwrite

    if (active) {
#pragma unroll
        for (int mi = 0; mi < 2; ++mi)
#pragma unroll
            for (int ni = 0; ni < 2; ++ni) {
                int n = np * 32 + ni * 16 + nn;
#pragma unroll
                for (int r = 0; r < 4; ++r) {
                    int m = mt * 32 + mi * 16 + kq * 4 + r;  // C/D row map
                    float pre = ALO ? (accM[mi][ni][r] + accC[mi][ni][r]) : accM[mi][ni][r];
                    float h = ftanh(pre);
                    if (SCATTER) {
                        unsafeAtomicAdd(out + (size_t)s_nodes[m] * 64 + n, h);
                    } else {
                        _Float16 hh = (_Float16)h;
                        sOh[m * HSTR + n] = __builtin_bit_cast(ushort, hh);
                    }
                }
            }
    }
}

__global__ __launch_bounds__(512, 4) void edge_mlp_packed(
    const int* __restrict__ af_, const int* __restrict__ at_,
    const float* __restrict__ h_local, const float* __restrict__ h_global,
    const float* __restrict__ x_local, const float* __restrict__ x_global,
    const float* __restrict__ tsc,
    const float* __restrict__ fb0, const float* __restrict__ fb1, const float* __restrict__ fb2,
    const float* __restrict__ tb0, const float* __restrict__ tb1, const float* __restrict__ tb2,
    const ushort* __restrict__ wpk, float* __restrict__ out)
{
    __shared__ ushort sAh[TE * ASTR], sAl[TE * ASTR];   // 21504 B each
    __shared__ ushort sHh[TE * HSTR];                   // 17408 B (single plane)
    __shared__ int s_af[TE], s_at[TE];                  // total 60928 B

    const int tid = threadIdx.x;
    const int e = tid >> 3, part = tid & 7;
    const int eg = blockIdx.x * TE + e;
    {
        int af = af_[eg], at = at_[eg];
        if (part == 0) { s_af[e] = af; s_at[e] = at; }
        int node = (part < 4) ? af : at;
        int k0 = ((part & 3) << 4) + ((part < 4) ? 0 : 64);
        const float4* hp = (const float4*)(h_local + (size_t)node * 64 + ((part & 3) << 4));
        float4 q0 = hp[0], q1 = hp[1], q2 = hp[2], q3 = hp[3];
        float v[16] = {q0.x,q0.y,q0.z,q0.w, q1.x,q1.y,q1.z,q1.w,
                       q2.x,q2.y,q2.z,q2.w, q3.x,q3.y,q3.z,q3.w};
        u32x4 H0, H1, L0, L1;
#pragma unroll
        for (int i = 0; i < 4; ++i) {
            ushort h0, l0, h1, l1;
            hsplit(v[2*i], h0, l0); hsplit(v[2*i+1], h1, l1);
            H0[i] = (uint)h0 | ((uint)h1 << 16);
            L0[i] = (uint)l0 | ((uint)l1 << 16);
        }
#pragma unroll
        for (int i = 0; i < 4; ++i) {
            ushort h0, l0, h1, l1;
            hsplit(v[8+2*i], h0, l0); hsplit(v[8+2*i+1], h1, l1);
            H1[i] = (uint)h0 | ((uint)h1 << 16);
            L1[i] = (uint)l0 | ((uint)l1 << 16);
        }
        *(u32x4*)(sAh + e * ASTR + k0)     = H0;
        *(u32x4*)(sAh + e * ASTR + k0 + 8) = H1;
        *(u32x4*)(sAl + e * ASTR + k0)     = L0;
        *(u32x4*)(sAl + e * ASTR + k0 + 8) = L1;
        if (part < 2) {
            int k0t = 128 + part * 16;
            float w[16];
#pragma unroll
            for (int i = 0; i < 16; ++i) {
                int k = k0t + i;
                float x;
                if      (k < 132)  x = x_local[(size_t)eg * 4 + (k - 128)];
                else if (k < 148)  x = h_global[k - 132];
                else if (k < 152)  x = x_global[k - 148];
                else if (k == 152) x = tsc[0];
                else               x = 0.f;
                w[i] = x;
            }
            u32x4 H2, H3, L2, L3;
#pragma unroll
            for (int i = 0; i < 4; ++i) {
                ushort h0, l0, h1, l1;
                hsplit(w[2*i], h0, l0); hsplit(w[2*i+1], h1, l1);
                H2[i] = (uint)h0 | ((uint)h1 << 16);
                L2[i] = (uint)l0 | ((uint)l1 << 16);
            }
#pragma unroll
            for (int i = 0; i < 4; ++i) {
                ushort h0, l0, h1, l1;
                hsplit(w[8+2*i], h0, l0); hsplit(w[8+2*i+1], h1, l1);
                H3[i] = (uint)h0 | ((uint)h1 << 16);
                L3[i] = (uint)l0 | ((uint)l1 << 16);
            }
            *(u32x4*)(sAh + e * ASTR + k0t)     = H2;
            *(u32x4*)(sAh + e * ASTR + k0t + 8) = H3;
            *(u32x4*)(sAl + e * ASTR + k0t)     = L2;
            *(u32x4*)(sAl + e * ASTR + k0t + 8) = L3;
        }
    }
    __syncthreads();
    // f MLP
    layer_p<5,4,true ,false,false>(sAh, sAl, ASTR, wpk + F0_OFF, fb0, sHh, nullptr, nullptr, tid);
    __syncthreads();
    layer_p<4,4,false,true ,false>(sHh, nullptr, HSTR, wpk + F1_OFF, fb1, sHh, nullptr, nullptr, tid);
    __syncthreads();
    layer_p<4,2,false,false,true >(sHh, nullptr, HSTR, wpk + F2_OFF, fb2, nullptr, out, s_af, tid);
    __syncthreads();
    // t MLP (sA planes intact)
    layer_p<5,4,true ,false,false>(sAh, sAl, ASTR, wpk + T0_OFF, tb0, sHh, nullptr, nullptr, tid);
    __syncthreads();
    layer_p<4,4,false,true ,false>(sHh, nullptr, HSTR, wpk + T1_OFF, tb1, sHh, nullptr, nullptr, tid);
    __syncthreads();
    layer_p<4,2,false,false,true >(sHh, nullptr, HSTR, wpk + T2_OFF, tb2, nullptr, out, s_at, tid);
}

// ================= gather fallback (R4, verified passing; bf16 3-chain) =================
template<int KC, int NT, int KACT, bool SCATTER>
__device__ __forceinline__ void layer(
    const float* __restrict__ sA, int astr,
    const float* __restrict__ gW, const float* __restrict__ bias,
    float* __restrict__ sO,
    float* __restrict__ out, const int* __restrict__ s_nodes, int tid)
{
    constexpr int NTW = NT / 2;
    constexpr int N = NT * 16;
    const int lane = tid & 63;
    const int wave = tid >> 6;
    const int mt   = wave >> 1;
    const int ntb  = (wave & 1) * NTW;
    const int arow = mt * 16 + (lane & 15);
    const int kg   = (lane >> 4) * 8;
    const int nn   = lane & 15;

    f32x4 aHH[NTW], aLH[NTW], aHL[NTW];
#pragma unroll
    for (int i = 0; i < NTW; ++i)
#pragma unroll
        for (int r = 0; r < 4; ++r) { aHH[i][r] = 0.f; aLH[i][r] = 0.f; aHL[i][r] = 0.f; }

#pragma unroll
    for (int kc = 0; kc < KC; ++kc) {
        const float* ap = sA + arow * astr + kc * 32 + kg;
        float av[8];
        float4 a0 = *(const float4*)ap;
        float4 a1 = *(const float4*)(ap + 4);
        av[0]=a0.x; av[1]=a0.y; av[2]=a0.z; av[3]=a0.w;
        av[4]=a1.x; av[5]=a1.y; av[6]=a1.z; av[7]=a1.w;
        bf16x8 ah, al; split8(av, ah, al);
#pragma unroll
        for (int i = 0; i < NTW; ++i) {
            int n = (ntb + i) * 16 + nn;
            float wv[8];
#pragma unroll
            for (int j = 0; j < 8; ++j) {
                int k = kc * 32 + kg + j;
                float w = 0.f;
                if (KC * 32 <= KACT || k < KACT)
                    w = gW[(size_t)k * N + n];
                wv[j] = w;
            }
            bf16x8 bh, bl; split8(wv, bh, bl);
            aHH[i] = __builtin_amdgcn_mfma_f32_16x16x32_bf16(ah, bh, aHH[i], 0, 0, 0);
            aLH[i] = __builtin_amdgcn_mfma_f32_16x16x32_bf16(al, bh, aLH[i], 0, 0, 0);
            aHL[i] = __builtin_amdgcn_mfma_f32_16x16x32_bf16(ah, bl, aHL[i], 0, 0, 0);
        }
    }

    if (!SCATTER) __syncthreads();

#pragma unroll
    for (int i = 0; i < NTW; ++i) {
        int n = (ntb + i) * 16 + nn;
        float bv = bias[n];
#pragma unroll
        for (int r = 0; r < 4; ++r) {
            int m = mt * 16 + ((lane >> 4) << 2) + r;
            float h = ftanh(aHH[i][r] + aLH[i][r] + aHL[i][r] + bv);
            if (SCATTER) {
                unsafeAtomicAdd(out + (size_t)s_nodes[m] * 64 + n, h);
            } else {
                sO[m * SH + n] = h;
            }
        }
    }
}

__global__ __launch_bounds__(512) void edge_mlp_gather(
    const int* __restrict__ af_, const int* __restrict__ at_,
    const float* __restrict__ h_local, const float* __restrict__ h_global,
    const float* __restrict__ x_local, const float* __restrict__ x_global,
    const float* __restrict__ tsc,
    const float* __restrict__ fW0, const float* __restrict__ fb0,
    const float* __restrict__ fW1, const float* __restrict__ fb1,
    const float* __restrict__ fW2, const float* __restrict__ fb2,
    const float* __restrict__ tW0, const float* __restrict__ tb0,
    const float* __restrict__ tW1, const float* __restrict__ tb1,
    const float* __restrict__ tW2, const float* __restrict__ tb2,
    float* __restrict__ out)
{
    __shared__ float sA[TE * SA];
    __shared__ float sH[TE * SH];
    __shared__ int s_af[TE], s_at[TE];

    const int tid = threadIdx.x;
    const int e = tid >> 3, part = tid & 7;
    const int eg = blockIdx.x * TE + e;
    {
        int af = af_[eg], at = at_[eg];
        if (part == 0) { s_af[e] = af; s_at[e] = at; }
        int node = (part < 4) ? af : at;
        int k0 = ((part & 3) << 4) + ((part < 4) ? 0 : 64);
        const float4* hp = (const float4*)(h_local + (size_t)node * 64 + ((part & 3) << 4));
        float4* dst = (float4*)(sA + e * SA + k0);
        dst[0] = hp[0]; dst[1] = hp[1]; dst[2] = hp[2]; dst[3] = hp[3];
        if (part < 2) {
            int k0t = 128 + part * 16;
#pragma unroll
            for (int i = 0; i < 16; ++i) {
                int k = k0t + i;
                float x;
                if      (k < 132)  x = x_local[(size_t)eg * 4 + (k - 128)];
                else if (k < 148)  x = h_global[k - 132];
                else if (k < 152)  x = x_global[k - 148];
                else if (k == 152) x = tsc[0];
                else               x = 0.f;
                sA[e * SA + k] = x;
            }
        }
    }
    __syncthreads();
    layer<5,8,153,false>(sA, SA, fW0, fb0, sH, nullptr, nullptr, tid);
    __syncthreads();
    layer<4,8,128,false>(sH, SH, fW1, fb1, sH, nullptr, nullptr, tid);
    __syncthreads();
    layer<4,4,128,true >(sH, SH, fW2, fb2, nullptr, out, s_af, tid);
    __syncthreads();
    layer<5,8,153,false>(sA, SA, tW0, tb0, sH, nullptr, nullptr, tid);
    __syncthreads();
    layer<4,8,128,false>(sH, SH, tW1, tb1, sH, nullptr, nullptr, tid);
    __syncthreads();
    layer<4,4,128,true >(sH, SH, tW2, tb2, nullptr, out, s_at, tid);
}

__global__ __launch_bounds__(256) void tanh_kernel(float* __restrict__ out, int n4) {
    int i = blockIdx.x * blockDim.x + threadIdx.x;
    int stride = gridDim.x * blockDim.x;
    float4* p = (float4*)out;
    for (; i < n4; i += stride) {
        float4 v = p[i];
        v.x = ftanh(v.x); v.y = ftanh(v.y); v.z = ftanh(v.z); v.w = ftanh(v.w);
        p[i] = v;
    }
}

extern "C" void kernel_launch(void* const* d_in, const int* in_sizes, int n_in,
                              void* d_out, int out_size, void* d_ws, size_t ws_size,
                              hipStream_t stream) {
    const int*   addr_from = (const int*)d_in[0];
    const int*   addr_to   = (const int*)d_in[1];
    const float* h_local   = (const float*)d_in[2];
    const float* h_global  = (const float*)d_in[3];
    const float* x_local   = (const float*)d_in[4];
    const float* x_global  = (const float*)d_in[5];
    const float* tsc       = (const float*)d_in[6];
    const float* fW0 = (const float*)d_in[7];
    const float* fb0 = (const float*)d_in[8];
    const float* fW1 = (const float*)d_in[9];
    const float* fb1 = (const float*)d_in[10];
    const float* fW2 = (const float*)d_in[11];
    const float* fb2 = (const float*)d_in[12];
    const float* tW0 = (const float*)d_in[13];
    const float* tb0 = (const float*)d_in[14];
    const float* tW1 = (const float*)d_in[15];
    const float* tb1 = (const float*)d_in[16];
    const float* tW2 = (const float*)d_in[17];
    const float* tb2 = (const float*)d_in[18];
    float* out = (float*)d_out;

    hipMemsetAsync(d_out, 0, (size_t)NN * 64 * sizeof(float), stream);

    if (ws_size >= (size_t)WPK_BYTES) {
        ushort* wpk = (ushort*)d_ws;
        pack_w<<<WPK_TOTAL / 256, 256, 0, stream>>>(fW0, fW1, fW2, tW0, tW1, tW2, wpk);
        edge_mlp_packed<<<NE / TE, 512, 0, stream>>>(
            addr_from, addr_to, h_local, h_global, x_local, x_global, tsc,
            fb0, fb1, fb2, tb0, tb1, tb2, wpk, out);
    } else {
        edge_mlp_gather<<<NE / TE, 512, 0, stream>>>(
            addr_from, addr_to, h_local, h_global, x_local, x_global, tsc,
            fW0, fb0, fW1, fb1, fW2, fb2, tW0, tb0, tW1, tb1, tW2, tb2, out);
    }
    tanh_kernel<<<2048, 256, 0, stream>>>(out, NN * 64 / 4);
}

// Round 13
// 416.133 us; speedup vs baseline: 1.7431x; 1.0383x over previous
//
#include <hip/hip_runtime.h>
#include <hip/hip_bf16.h>

typedef unsigned int uint;
typedef unsigned short ushort;
typedef _Float16 f16x8 __attribute__((ext_vector_type(8)));
typedef short bf16x8 __attribute__((ext_vector_type(8)));
typedef float f32x4 __attribute__((ext_vector_type(4)));
typedef uint u32x4 __attribute__((ext_vector_type(4)));

#define NE 800000
#define NN 100000
#define TE 64
#define ASTR 168   // ushort row stride of input planes (336 B, 21x16B)
#define HSTR 136   // ushort row stride of hidden planes (272 B, 17x16B)
#define SA 164     // f32 row stride (gather-fallback kernel)
#define SH 132

// packed fp16 weight offsets (ushort elems) in d_ws — R11 layout (verified):
// idx = base + ((np*KC + kc)*2 + i)*512 + lane*8 + j     (single fp16 plane)
// value = fp16( W[k = kc*32 + (lane>>4)*8 + j][n = np*32 + i*16 + (lane&15)] )
#define F0_OFF 0
#define F1_OFF 20480
#define F2_OFF 36864
#define T0_OFF 45056
#define T1_OFF 65536
#define T2_OFF 81920
#define WPK_TOTAL 90112
#define WPK_BYTES (WPK_TOTAL * 2)

#define MF(a, b, c) __builtin_amdgcn_mfma_f32_16x16x32_f16(a, b, c, 0, 0, 0)

// clamp-free tanh: x->+inf => e=inf, rcp=0 => 1; x->-inf => e=0, rcp(1)=1 => -1.
__device__ __forceinline__ float ftanh(float x) {
    float e = __builtin_amdgcn_exp2f(x * 2.885390081777927f);   // exp(2x)
    return __builtin_fmaf(-2.f, __builtin_amdgcn_rcpf(e + 1.f), 1.f);
}

// fp32 -> fp16 hi (RTNE) + fp16 lo (residual)
__device__ __forceinline__ void hsplit(float x, ushort& hi, ushort& lo) {
    _Float16 h = (_Float16)x;
    float r = x - (float)h;
    _Float16 l = (_Float16)r;
    hi = __builtin_bit_cast(ushort, h);
    lo = __builtin_bit_cast(ushort, l);
}

// bf16 split (gather-fallback kernel only)
__device__ __forceinline__ void bfsplit(float x, ushort& hi, ushort& lo) {
    uint xb = __builtin_bit_cast(uint, x);
    hi = (ushort)(xb >> 16);
    float hif = __builtin_bit_cast(float, xb & 0xFFFF0000u);
    float res = x - hif;
    lo = (ushort)(__builtin_bit_cast(uint, res) >> 16);
}

__device__ __forceinline__ void split8(const float* v, bf16x8& fh, bf16x8& fl) {
    u32x4 H, L;
#pragma unroll
    for (int i = 0; i < 4; ++i) {
        ushort h0, l0, h1, l1;
        bfsplit(v[2*i],   h0, l0);
        bfsplit(v[2*i+1], h1, l1);
        H[i] = (uint)h0 | ((uint)h1 << 16);
        L[i] = (uint)l0 | ((uint)l1 << 16);
    }
    fh = __builtin_bit_cast(bf16x8, H);
    fl = __builtin_bit_cast(bf16x8, L);
}

// ---- weight pack: single fp16 plane, wave-contiguous — unchanged from R11 ----
__global__ __launch_bounds__(256) void pack_w(
    const float* __restrict__ fW0, const float* __restrict__ fW1, const float* __restrict__ fW2,
    const float* __restrict__ tW0, const float* __restrict__ tW1, const float* __restrict__ tW2,
    ushort* __restrict__ wpk)
{
    int idx = blockIdx.x * 256 + threadIdx.x;   // < WPK_TOTAL
    const float* src; int NP, KC, Kact, base;
    if      (idx < F1_OFF) { src = fW0; NP = 4; KC = 5; Kact = 153; base = F0_OFF; }
    else if (idx < F2_OFF) { src = fW1; NP = 4; KC = 4; Kact = 128; base = F1_OFF; }
    else if (idx < T0_OFF) { src = fW2; NP = 2; KC = 4; Kact = 128; base = F2_OFF; }
    else if (idx < T1_OFF) { src = tW0; NP = 4; KC = 5; Kact = 153; base = T0_OFF; }
    else if (idx < T2_OFF) { src = tW1; NP = 4; KC = 4; Kact = 128; base = T1_OFF; }
    else                   { src = tW2; NP = 2; KC = 4; Kact = 128; base = T2_OFF; }
    int rel  = idx - base;
    int j    = rel & 7;
    int lane = (rel >> 3) & 63;
    int sub  = rel >> 9;
    int i    = sub & 1;
    int s2   = sub >> 1;
    int kc   = s2 % KC;
    int np   = s2 / KC;
    int k = kc * 32 + ((lane >> 4) << 3) + j;
    int n = np * 32 + i * 16 + (lane & 15);
    int N = NP * 32;
    float w = (k < Kact) ? src[(size_t)k * N + n] : 0.f;
    _Float16 h = (_Float16)w;   // RTNE
    wpk[idx] = __builtin_bit_cast(ushort, h);
}

// ---- single-plane K-loop: 32 rows x 64 cols per wave, acc += A*W ----
template<int KC>
__device__ __forceinline__ void kloop1(const ushort* __restrict__ ap, int astr,
                                       const ushort* __restrict__ gWl,
                                       f32x4 (&acc)[2][2])
{
#pragma unroll
    for (int kc = 0; kc < KC; ++kc) {
        f16x8 a0 = *(const f16x8*)(ap + kc * 32);
        f16x8 a1 = *(const f16x8*)(ap + 16 * astr + kc * 32);
        f16x8 w0 = *(const f16x8*)(gWl + kc * 1024);
        f16x8 w1 = *(const f16x8*)(gWl + kc * 1024 + 512);
        acc[0][0] = MF(a0, w0, acc[0][0]);
        acc[1][0] = MF(a1, w0, acc[1][0]);
        acc[0][1] = MF(a0, w1, acc[0][1]);
        acc[1][1] = MF(a1, w1, acc[1][1]);
    }
}

__device__ __forceinline__ void acc_init(f32x4 (&acc)[2][2],
                                         const float* __restrict__ bias,
                                         int npv, int nn)
{
#pragma unroll
    for (int ni = 0; ni < 2; ++ni) {
        float bv = bias[npv * 32 + ni * 16 + nn];
#pragma unroll
        for (int mi = 0; mi < 2; ++mi)
#pragma unroll
            for (int r = 0; r < 4; ++r) acc[mi][ni][r] = bv;
    }
}

__device__ __forceinline__ void epi_store(const f32x4 (&acc)[2][2],
                                          ushort* __restrict__ sO, int ostr,
                                          int mt, int nn, int kq, int npv)
{
#pragma unroll
    for (int mi = 0; mi < 2; ++mi)
#pragma unroll
        for (int ni = 0; ni < 2; ++ni) {
            int n = npv * 32 + ni * 16 + nn;
#pragma unroll
            for (int r = 0; r < 4; ++r) {
                int m = mt * 32 + mi * 16 + kq * 4 + r;   // C/D row map
                _Float16 hh = (_Float16)ftanh(acc[mi][ni][r]);
                sO[m * ostr + n] = __builtin_bit_cast(ushort, hh);
            }
        }
}

// ================= packed-weight main kernel (merged f/t phases) =================
__global__ __launch_bounds__(512, 4) void edge_mlp_packed(
    const int* __restrict__ af_, const int* __restrict__ at_,
    const float* __restrict__ h_local, const float* __restrict__ h_global,
    const float* __restrict__ x_local, const float* __restrict__ x_global,
    const float* __restrict__ tsc,
    const float* __restrict__ fb0, const float* __restrict__ fb1, const float* __restrict__ fb2,
    const float* __restrict__ tb0, const float* __restrict__ tb1, const float* __restrict__ tb2,
    const ushort* __restrict__ wpk, float* __restrict__ out)
{
    __shared__ ushort sAh[TE * ASTR], sAl[TE * ASTR];   // 21504 B each
    __shared__ ushort sHf[TE * HSTR], sHt[TE * HSTR];   // 17408 B each
    __shared__ int s_af[TE], s_at[TE];                  // total 78336 B

    const int tid = threadIdx.x;
    const int e = tid >> 3, part = tid & 7;
    const int eg = blockIdx.x * TE + e;
    {
        int af = af_[eg], at = at_[eg];
        if (part == 0) { s_af[e] = af; s_at[e] = at; }
        int node = (part < 4) ? af : at;
        int k0 = ((part & 3) << 4) + ((part < 4) ? 0 : 64);
        const float4* hp = (const float4*)(h_local + (size_t)node * 64 + ((part & 3) << 4));
        float4 q0 = hp[0], q1 = hp[1], q2 = hp[2], q3 = hp[3];
        float v[16] = {q0.x,q0.y,q0.z,q0.w, q1.x,q1.y,q1.z,q1.w,
                       q2.x,q2.y,q2.z,q2.w, q3.x,q3.y,q3.z,q3.w};
        u32x4 H0, H1, L0, L1;
#pragma unroll
        for (int i = 0; i < 4; ++i) {
            ushort h0, l0, h1, l1;
            hsplit(v[2*i], h0, l0); hsplit(v[2*i+1], h1, l1);
            H0[i] = (uint)h0 | ((uint)h1 << 16);
            L0[i] = (uint)l0 | ((uint)l1 << 16);
        }
#pragma unroll
        for (int i = 0; i < 4; ++i) {
            ushort h0, l0, h1, l1;
            hsplit(v[8+2*i], h0, l0); hsplit(v[8+2*i+1], h1, l1);
            H1[i] = (uint)h0 | ((uint)h1 << 16);
            L1[i] = (uint)l0 | ((uint)l1 << 16);
        }
        *(u32x4*)(sAh + e * ASTR + k0)     = H0;
        *(u32x4*)(sAh + e * ASTR + k0 + 8) = H1;
        *(u32x4*)(sAl + e * ASTR + k0)     = L0;
        *(u32x4*)(sAl + e * ASTR + k0 + 8) = L1;
        if (part < 2) {
            int k0t = 128 + part * 16;
            float w[16];
#pragma unroll
            for (int i = 0; i < 16; ++i) {
                int k = k0t + i;
                float x;
                if      (k < 132)  x = x_local[(size_t)eg * 4 + (k - 128)];
                else if (k < 148)  x = h_global[k - 132];
                else if (k < 152)  x = x_global[k - 148];
                else if (k == 152) x = tsc[0];
                else               x = 0.f;
                w[i] = x;
            }
            u32x4 H2, H3, L2, L3;
#pragma unroll
            for (int i = 0; i < 4; ++i) {
                ushort h0, l0, h1, l1;
                hsplit(w[2*i], h0, l0); hsplit(w[2*i+1], h1, l1);
                H2[i] = (uint)h0 | ((uint)h1 << 16);
                L2[i] = (uint)l0 | ((uint)l1 << 16);
            }
#pragma unroll
            for (int i = 0; i < 4; ++i) {
                ushort h0, l0, h1, l1;
                hsplit(w[8+2*i], h0, l0); hsplit(w[8+2*i+1], h1, l1);
                H3[i] = (uint)h0 | ((uint)h1 << 16);
                L3[i] = (uint)l0 | ((uint)l1 << 16);
            }
            *(u32x4*)(sAh + e * ASTR + k0t)     = H2;
            *(u32x4*)(sAh + e * ASTR + k0t + 8) = H3;
            *(u32x4*)(sAl + e * ASTR + k0t)     = L2;
            *(u32x4*)(sAl + e * ASTR + k0t + 8) = L3;
        }
    }
    __syncthreads();

    const int lane = tid & 63;
    const int wave = tid >> 6;
    const int mt   = wave >> 2;          // 0..1  (32-edge row tile)
    const int np   = wave & 3;           // 0..3  (32-col tile)
    const int nn   = lane & 15;
    const int kq   = (lane >> 4) & 3;
    const int npu  = __builtin_amdgcn_readfirstlane(np);

    // ---- Phase A: L0 for both MLPs, shared A hi/lo fragments ----
    {
        f32x4 af[2][2], at2[2][2];
        acc_init(af,  fb0, np, nn);
        acc_init(at2, tb0, np, nn);
        const ushort* apH = sAh + (mt * 32 + nn) * ASTR + kq * 8;
        const ushort* apL = sAl + (mt * 32 + nn) * ASTR + kq * 8;
        const ushort* gF = wpk + F0_OFF + npu * (5 * 1024) + lane * 8;
        const ushort* gT = wpk + T0_OFF + npu * (5 * 1024) + lane * 8;
#pragma unroll
        for (int kc = 0; kc < 5; ++kc) {
            f16x8 a0 = *(const f16x8*)(apH + kc * 32);
            f16x8 a1 = *(const f16x8*)(apH + 16 * ASTR + kc * 32);
            f16x8 l0 = *(const f16x8*)(apL + kc * 32);
            f16x8 l1 = *(const f16x8*)(apL + 16 * ASTR + kc * 32);
            f16x8 w0 = *(const f16x8*)(gF + kc * 1024);
            f16x8 w1 = *(const f16x8*)(gF + kc * 1024 + 512);
            f16x8 u0 = *(const f16x8*)(gT + kc * 1024);
            f16x8 u1 = *(const f16x8*)(gT + kc * 1024 + 512);
            af[0][0]  = MF(a0, w0, af[0][0]);  af[1][0]  = MF(a1, w0, af[1][0]);
            af[0][1]  = MF(a0, w1, af[0][1]);  af[1][1]  = MF(a1, w1, af[1][1]);
            at2[0][0] = MF(a0, u0, at2[0][0]); at2[1][0] = MF(a1, u0, at2[1][0]);
            at2[0][1] = MF(a0, u1, at2[0][1]); at2[1][1] = MF(a1, u1, at2[1][1]);
            af[0][0]  = MF(l0, w0, af[0][0]);  af[1][0]  = MF(l1, w0, af[1][0]);
            af[0][1]  = MF(l0, w1, af[0][1]);  af[1][1]  = MF(l1, w1, af[1][1]);
            at2[0][0] = MF(l0, u0, at2[0][0]); at2[1][0] = MF(l1, u0, at2[1][0]);
            at2[0][1] = MF(l0, u1, at2[0][1]); at2[1][1] = MF(l1, u1, at2[1][1]);
        }
        // sHf/sHt are fresh buffers — no hazard, write immediately
        epi_store(af,  sHf, HSTR, mt, nn, kq, np);
        epi_store(at2, sHt, HSTR, mt, nn, kq, np);
    }
    __syncthreads();

    // ---- Phase B: L1 for both MLPs (in-place on sHf/sHt) ----
    {
        f32x4 af[2][2], at2[2][2];
        acc_init(af,  fb1, np, nn);
        acc_init(at2, tb1, np, nn);
        const ushort* apf = sHf + (mt * 32 + nn) * HSTR + kq * 8;
        const ushort* apt = sHt + (mt * 32 + nn) * HSTR + kq * 8;
        kloop1<4>(apf, HSTR, wpk + F1_OFF + npu * 4096 + lane * 8, af);
        kloop1<4>(apt, HSTR, wpk + T1_OFF + npu * 4096 + lane * 8, at2);
        __syncthreads();   // all reads of sHf/sHt done before in-place overwrite
        epi_store(af,  sHf, HSTR, mt, nn, kq, np);
        epi_store(at2, sHt, HSTR, mt, nn, kq, np);
    }
    __syncthreads();

    // ---- Phase C: L2 scatter, wave-split (np<2 -> f, np>=2 -> t), all waves active ----
    {
        const int sel  = __builtin_amdgcn_readfirstlane(np >> 1);
        const int np2  = __builtin_amdgcn_readfirstlane(np & 1);
        const ushort* sH  = sel ? sHt : sHf;
        const ushort* gW2 = wpk + (sel ? T2_OFF : F2_OFF) + np2 * 4096 + lane * 8;
        const float* b2   = sel ? tb2 : fb2;
        const int* nds    = sel ? s_at : s_af;

        f32x4 acc[2][2];
        acc_init(acc, b2, np2, nn);
        const ushort* ap = sH + (mt * 32 + nn) * HSTR + kq * 8;
        kloop1<4>(ap, HSTR, gW2, acc);
#pragma unroll
        for (int mi = 0; mi < 2; ++mi)
#pragma unroll
            for (int ni = 0; ni < 2; ++ni) {
                int n = np2 * 32 + ni * 16 + nn;
#pragma unroll
                for (int r = 0; r < 4; ++r) {
                    int m = mt * 32 + mi * 16 + kq * 4 + r;
                    float h = ftanh(acc[mi][ni][r]);
                    unsafeAtomicAdd(out + (size_t)nds[m] * 64 + n, h);
                }
            }
    }
}

// ================= gather fallback (R4, verified passing; bf16 3-chain) =================
template<int KC, int NT, int KACT, bool SCATTER>
__device__ __forceinline__ void layer(
    const float* __restrict__ sA, int astr,
    const float* __restrict__ gW, const float* __restrict__ bias,
    float* __restrict__ sO,
    float* __restrict__ out, const int* __restrict__ s_nodes, int tid)
{
    constexpr int NTW = NT / 2;
    constexpr int N = NT * 16;
    const int lane = tid & 63;
    const int wave = tid >> 6;
    const int mt   = wave >> 1;
    const int ntb  = (wave & 1) * NTW;
    const int arow = mt * 16 + (lane & 15);
    const int kg   = (lane >> 4) * 8;
    const int nn   = lane & 15;

    f32x4 aHH[NTW], aLH[NTW], aHL[NTW];
#pragma unroll
    for (int i = 0; i < NTW; ++i)
#pragma unroll
        for (int r = 0; r < 4; ++r) { aHH[i][r] = 0.f; aLH[i][r] = 0.f; aHL[i][r] = 0.f; }

#pragma unroll
    for (int kc = 0; kc < KC; ++kc) {
        const float* ap = sA + arow * astr + kc * 32 + kg;
        float av[8];
        float4 a0 = *(const float4*)ap;
        float4 a1 = *(const float4*)(ap + 4);
        av[0]=a0.x; av[1]=a0.y; av[2]=a0.z; av[3]=a0.w;
        av[4]=a1.x; av[5]=a1.y; av[6]=a1.z; av[7]=a1.w;
        bf16x8 ah, al; split8(av, ah, al);
#pragma unroll
        for (int i = 0; i < NTW; ++i) {
            int n = (ntb + i) * 16 + nn;
            float wv[8];
#pragma unroll
            for (int j = 0; j < 8; ++j) {
                int k = kc * 32 + kg + j;
                float w = 0.f;
                if (KC * 32 <= KACT || k < KACT)
                    w = gW[(size_t)k * N + n];
                wv[j] = w;
            }
            bf16x8 bh, bl; split8(wv, bh, bl);
            aHH[i] = __builtin_amdgcn_mfma_f32_16x16x32_bf16(ah, bh, aHH[i], 0, 0, 0);
            aLH[i] = __builtin_amdgcn_mfma_f32_16x16x32_bf16(al, bh, aLH[i], 0, 0, 0);
            aHL[i] = __builtin_amdgcn_mfma_f32_16x16x32_bf16(ah, bl, aHL[i], 0, 0, 0);
        }
    }

    if (!SCATTER) __syncthreads();

#pragma unroll
    for (int i = 0; i < NTW; ++i) {
        int n = (ntb + i) * 16 + nn;
        float bv = bias[n];
#pragma unroll
        for (int r = 0; r < 4; ++r) {
            int m = mt * 16 + ((lane >> 4) << 2) + r;
            float h = ftanh(aHH[i][r] + aLH[i][r] + aHL[i][r] + bv);
            if (SCATTER) {
                unsafeAtomicAdd(out + (size_t)s_nodes[m] * 64 + n, h);
            } else {
                sO[m * SH + n] = h;
            }
        }
    }
}

__global__ __launch_bounds__(512) void edge_mlp_gather(
    const int* __restrict__ af_, const int* __restrict__ at_,
    const float* __restrict__ h_local, const float* __restrict__ h_global,
    const float* __restrict__ x_local, const float* __restrict__ x_global,
    const float* __restrict__ tsc,
    const float* __restrict__ fW0, const float* __restrict__ fb0,
    const float* __restrict__ fW1, const float* __restrict__ fb1,
    const float* __restrict__ fW2, const float* __restrict__ fb2,
    const float* __restrict__ tW0, const float* __restrict__ tb0,
    const float* __restrict__ tW1, const float* __restrict__ tb1,
    const float* __restrict__ tW2, const float* __restrict__ tb2,
    float* __restrict__ out)
{
    __shared__ float sA[TE * SA];
    __shared__ float sH[TE * SH];
    __shared__ int s_af[TE], s_at[TE];

    const int tid = threadIdx.x;
    const int e = tid >> 3, part = tid & 7;
    const int eg = blockIdx.x * TE + e;
    {
        int af = af_[eg], at = at_[eg];
        if (part == 0) { s_af[e] = af; s_at[e] = at; }
        int node = (part < 4) ? af : at;
        int k0 = ((part & 3) << 4) + ((part < 4) ? 0 : 64);
        const float4* hp = (const float4*)(h_local + (size_t)node * 64 + ((part & 3) << 4));
        float4* dst = (float4*)(sA + e * SA + k0);
        dst[0] = hp[0]; dst[1] = hp[1]; dst[2] = hp[2]; dst[3] = hp[3];
        if (part < 2) {
            int k0t = 128 + part * 16;
#pragma unroll
            for (int i = 0; i < 16; ++i) {
                int k = k0t + i;
                float x;
                if      (k < 132)  x = x_local[(size_t)eg * 4 + (k - 128)];
                else if (k < 148)  x = h_global[k - 132];
                else if (k < 152)  x = x_global[k - 148];
                else if (k == 152) x = tsc[0];
                else               x = 0.f;
                sA[e * SA + k] = x;
            }
        }
    }
    __syncthreads();
    layer<5,8,153,false>(sA, SA, fW0, fb0, sH, nullptr, nullptr, tid);
    __syncthreads();
    layer<4,8,128,false>(sH, SH, fW1, fb1, sH, nullptr, nullptr, tid);
    __syncthreads();
    layer<4,4,128,true >(sH, SH, fW2, fb2, nullptr, out, s_af, tid);
    __syncthreads();
    layer<5,8,153,false>(sA, SA, tW0, tb0, sH, nullptr, nullptr, tid);
    __syncthreads();
    layer<4,8,128,false>(sH, SH, tW1, tb1, sH, nullptr, nullptr, tid);
    __syncthreads();
    layer<4,4,128,true >(sH, SH, tW2, tb2, nullptr, out, s_at, tid);
}

__global__ __launch_bounds__(256) void tanh_kernel(float* __restrict__ out, int n4) {
    int i = blockIdx.x * blockDim.x + threadIdx.x;
    int stride = gridDim.x * blockDim.x;
    float4* p = (float4*)out;
    for (; i < n4; i += stride) {
        float4 v = p[i];
        v.x = ftanh(v.x); v.y = ftanh(v.y); v.z = ftanh(v.z); v.w = ftanh(v.w);
        p[i] = v;
    }
}

extern "C" void kernel_launch(void* const* d_in, const int* in_sizes, int n_in,
                              void* d_out, int out_size, void* d_ws, size_t ws_size,
                              hipStream_t stream) {
    const int*   addr_from = (const int*)d_in[0];
    const int*   addr_to   = (const int*)d_in[1];
    const float* h_local   = (const float*)d_in[2];
    const float* h_global  = (const float*)d_in[3];
    const float* x_local   = (const float*)d_in[4];
    const float* x_global  = (const float*)d_in[5];
    const float* tsc       = (const float*)d_in[6];
    const float* fW0 = (const float*)d_in[7];
    const float* fb0 = (const float*)d_in[8];
    const float* fW1 = (const float*)d_in[9];
    const float* fb1 = (const float*)d_in[10];
    const float* fW2 = (const float*)d_in[11];
    const float* fb2 = (const float*)d_in[12];
    const float* tW0 = (const float*)d_in[13];
    const float* tb0 = (const float*)d_in[14];
    const float* tW1 = (const float*)d_in[15];
    const float* tb1 = (const float*)d_in[16];
    const float* tW2 = (const float*)d_in[17];
    const float* tb2 = (const float*)d_in[18];
    float* out = (float*)d_out;

    hipMemsetAsync(d_out, 0, (size_t)NN * 64 * sizeof(float), stream);

    if (ws_size >= (size_t)WPK_BYTES) {
        ushort* wpk = (ushort*)d_ws;
        pack_w<<<WPK_TOTAL / 256, 256, 0, stream>>>(fW0, fW1, fW2, tW0, tW1, tW2, wpk);
        edge_mlp_packed<<<NE / TE, 512, 0, stream>>>(
            addr_from, addr_to, h_local, h_global, x_local, x_global, tsc,
            fb0, fb1, fb2, tb0, tb1, tb2, wpk, out);
    } else {
        edge_mlp_gather<<<NE / TE, 512, 0, stream>>>(
            addr_from, addr_to, h_local, h_global, x_local, x_global, tsc,
            fW0, fb0, fW1, fb1, fW2, fb2, tW0, tb0, tW1, tb1, tW2, tb2, out);
    }
    tanh_kernel<<<2048, 256, 0, stream>>>(out, NN * 64 / 4);
}